// Round 13
// baseline (482.382 us; speedup 1.0000x reference)
//
#include <hip/hip_runtime.h>

#define NN 50000
#define NE 800000
#define NF 128
#define BF 16
#define NH 4
#define HC 128
#define CC 32
#define DEPTH 5
#define NEG 0.2f
#define NPART 256
#define PTILE 4096

typedef __attribute__((ext_vector_type(8))) short bf16x8;
typedef __attribute__((ext_vector_type(4))) float f32x4;

__device__ inline unsigned short f2bf(float f) {
  union { float f; unsigned u; } v; v.f = f;
  unsigned r = v.u + 0x7fff + ((v.u >> 16) & 1);
  return (unsigned short)(r >> 16);
}
__device__ inline float bf2f(unsigned short u) {
  union { unsigned u; float f; } v; v.u = (unsigned)u << 16; return v.f;
}

// ---------------- CSR build ----------------
// fused: per-node degree count + per-partition histogram, one edst pass
__global__ __launch_bounds__(256) void k_cnt0(const int* __restrict__ edst,
                                              int* __restrict__ deg,
                                              int* __restrict__ pcnt) {
  __shared__ int lc[NPART];
  int t = threadIdx.x;
  lc[t] = 0;
  __syncthreads();
  int base = blockIdx.x * PTILE;
#pragma unroll
  for (int j = 0; j < PTILE / 256; ++j) {
    int e = base + t + j * 256;
    if (e < NE) {
      int d = edst[e];
      atomicAdd(&deg[d], 1);
      atomicAdd(&lc[d >> 8], 1);
    }
  }
  __syncthreads();
  if (lc[t]) atomicAdd(&pcnt[t], lc[t]);
}

__global__ void k_partial(const int* __restrict__ deg, int* __restrict__ bsum) {
  __shared__ int s[256];
  int t = threadIdx.x;
  int i = blockIdx.x * 256 + t;
  s[t] = (i < NN) ? deg[i] : 0;
  __syncthreads();
  for (int d = 128; d > 0; d >>= 1) {
    if (t < d) s[t] += s[t + d];
    __syncthreads();
  }
  if (t == 0) bsum[blockIdx.x] = s[0];
}

__global__ void k_scan_top(int* __restrict__ bsum, int nb) {
  if (threadIdx.x == 0 && blockIdx.x == 0) {
    int run = 0;
    for (int i = 0; i < nb; ++i) { int v = bsum[i]; bsum[i] = run; run += v; }
  }
}

__global__ void k_scan_write(const int* __restrict__ deg, const int* __restrict__ bsum,
                             int* __restrict__ offs, int* __restrict__ cur) {
  __shared__ int s[256];
  int t = threadIdx.x;
  int i = blockIdx.x * 256 + t;
  int v = (i < NN) ? deg[i] : 0;
  s[t] = v;
  __syncthreads();
  for (int d = 1; d < 256; d <<= 1) {
    int x = (t >= d) ? s[t - d] : 0;
    __syncthreads();
    s[t] += x;
    __syncthreads();
  }
  if (i < NN) {
    int o = bsum[blockIdx.x] + s[t] - v;
    offs[i] = o;
    cur[i] = o;
  }
  if (i == 0) offs[NN] = NE;
}

__global__ void k_pscan(const int* __restrict__ pcnt, int* __restrict__ pbase,
                        int* __restrict__ pcur) {
  __shared__ int s[NPART];
  int t = threadIdx.x;
  int v = pcnt[t];
  s[t] = v;
  __syncthreads();
  for (int d = 1; d < NPART; d <<= 1) {
    int x = (t >= d) ? s[t - d] : 0;
    __syncthreads();
    s[t] += x;
    __syncthreads();
  }
  int ex = s[t] - v;
  pbase[t] = ex;
  pcur[t] = ex;
  if (t == NPART - 1) pbase[NPART] = s[NPART - 1];
}

__global__ __launch_bounds__(256) void k_p1(const int* __restrict__ edst,
                                            int* __restrict__ pcur,
                                            int2* __restrict__ staging) {
  __shared__ int lc[NPART];
  __shared__ int lbase[NPART];
  __shared__ int lrank[NPART];
  int t = threadIdx.x;
  lc[t] = 0;
  __syncthreads();
  int base = blockIdx.x * PTILE;
  int myd[PTILE / 256];
#pragma unroll
  for (int j = 0; j < PTILE / 256; ++j) {
    int e = base + t + j * 256;
    int d = (e < NE) ? edst[e] : -1;
    myd[j] = d;
    if (d >= 0) atomicAdd(&lc[d >> 8], 1);
  }
  __syncthreads();
  if (lc[t]) lbase[t] = atomicAdd(&pcur[t], lc[t]);
  lrank[t] = 0;
  __syncthreads();
#pragma unroll
  for (int j = 0; j < PTILE / 256; ++j) {
    int d = myd[j];
    if (d >= 0) {
      int p = d >> 8;
      int r = atomicAdd(&lrank[p], 1);
      staging[lbase[p] + r] = make_int2(base + t + j * 256, d);
    }
  }
}

__global__ __launch_bounds__(256) void k_p2(const int2* __restrict__ staging,
                                            const int* __restrict__ pbase,
                                            int* __restrict__ cur,
                                            int* __restrict__ csr_eid) {
  int p = blockIdx.x;
  int s = pbase[p], e = pbase[p + 1];
  for (int i = s + threadIdx.x; i < e; i += 256) {
    int2 st = staging[i];
    int slot = atomicAdd(&cur[st.y], 1);
    csr_eid[slot] = st.x;
  }
}

// ---------------- prep kernels (once) ----------------
__global__ void k_weff(const float* __restrict__ We, const float* __restrict__ ae,
                       float* __restrict__ weff) {
  int idx = threadIdx.x;
  if (idx >= DEPTH * BF * NH) return;
  int l = idx / (BF * NH);
  int r = idx - l * (BF * NH);
  int f = r >> 2, h = r & 3;
  const float* We_l = We + (size_t)l * BF * HC;
  const float* ae_l = ae + (size_t)l * NH * CC;
  float acc = 0.f;
  for (int c = 0; c < CC; ++c) acc += We_l[f * HC + h * CC + c] * ae_l[h * CC + c];
  weff[idx] = acc;
}

__global__ __launch_bounds__(256) void k_aeprep(const int* __restrict__ csr_eid,
                                                const int* __restrict__ esrc,
                                                const float* __restrict__ eattr,
                                                const float* __restrict__ weff,
                                                unsigned short* __restrict__ ae_csr,
                                                int* __restrict__ csr_src) {
  __shared__ float sw[DEPTH * BF * NH];
  int t = threadIdx.x;
  if (t < DEPTH * BF * NH) sw[t] = weff[t];
  __syncthreads();
  int i = blockIdx.x * 256 + t;
  if (i >= NE) return;
  int eid = csr_eid[i];
  csr_src[i] = esrc[eid];
  float at[16];
  const float4* ar = (const float4*)(eattr + (size_t)eid * BF);
#pragma unroll
  for (int q = 0; q < 4; ++q) {
    float4 v = ar[q];
    at[q * 4] = v.x; at[q * 4 + 1] = v.y; at[q * 4 + 2] = v.z; at[q * 4 + 3] = v.w;
  }
#pragma unroll
  for (int l = 0; l < DEPTH; ++l) {
    float a0 = 0.f, a1 = 0.f, a2 = 0.f, a3 = 0.f;
#pragma unroll
    for (int f = 0; f < BF; ++f) {
      float av = at[f];
      const float* wf = &sw[(l * BF + f) * NH];
      a0 += av * wf[0]; a1 += av * wf[1]; a2 += av * wf[2]; a3 += av * wf[3];
    }
    ushort4 u;
    u.x = f2bf(a0); u.y = f2bf(a1); u.z = f2bf(a2); u.w = f2bf(a3);
    ((ushort4*)ae_csr)[(size_t)l * NE + i] = u;
  }
}

__global__ void k_aeself(const unsigned short* __restrict__ ae_csr,
                         const int* __restrict__ offs,
                         unsigned short* __restrict__ ae_self) {
  int idx = blockIdx.x * 256 + threadIdx.x;
  if (idx >= NN * DEPTH) return;
  int l = idx / NN, n = idx - l * NN;
  int s = offs[n], e = offs[n + 1];
  const ushort4* base = (const ushort4*)ae_csr + (size_t)l * NE;
  float a0 = 0.f, a1 = 0.f, a2 = 0.f, a3 = 0.f;
  for (int i = s; i < e; ++i) {
    ushort4 u = base[i];
    a0 += bf2f(u.x); a1 += bf2f(u.y); a2 += bf2f(u.z); a3 += bf2f(u.w);
  }
  float inv = 1.0f / fmaxf((float)(e - s), 1.0f);
  ushort4 o;
  o.x = f2bf(a0 * inv); o.y = f2bf(a1 * inv); o.z = f2bf(a2 * inv); o.w = f2bf(a3 * inv);
  ((ushort4*)ae_self)[(size_t)l * NN + n] = o;
}

__global__ void k_x2bf(const float* __restrict__ x, unsigned short* __restrict__ xb) {
  int i = blockIdx.x * 256 + threadIdx.x;
  if (i >= NN * 32) return;
  float4 v = ((const float4*)x)[i];
  ushort4 u;
  u.x = f2bf(v.x); u.y = f2bf(v.y); u.z = f2bf(v.z); u.w = f2bf(v.w);
  ((ushort4*)xb)[i] = u;
}

__global__ void k_wprep(const float* __restrict__ W, unsigned short* __restrict__ Wt) {
  int idx = blockIdx.x * 256 + threadIdx.x;
  if (idx >= DEPTH * NF * HC) return;
  int l = idx >> 14;
  int rem = idx & 16383;
  int n = rem >> 7, k = rem & 127;
  Wt[(size_t)l * 16384 + (size_t)n * 128 + k] = f2bf(W[(size_t)l * 16384 + (size_t)k * 128 + n]);
}

// ---------------- per-layer kernels ----------------
// xp = A @ W via bf16 MFMA; 128-row x 128-col block, 4 waves (wave = 32-col strip).
// LDS C-tile epilogue: coalesced uint4 stores + a_s/a_d dots.
__global__ __launch_bounds__(256) void k_gemm_mfma(const unsigned short* __restrict__ Ab,
                                                   const unsigned short* __restrict__ Wt,
                                                   const float* __restrict__ as_w,
                                                   const float* __restrict__ ad_w,
                                                   unsigned short* __restrict__ xpb,
                                                   float* __restrict__ a_s,
                                                   float* __restrict__ a_d) {
  __shared__ unsigned short cl[128][144];
  __shared__ float swS[128], dwS[128];
  int t = threadIdx.x;
  if (t < 128) { swS[t] = as_w[t]; dwS[t] = ad_w[t]; }
  int wv = t >> 6;
  int l = t & 63;
  int r0 = blockIdx.x * 128;
  int lk = (l >> 4) * 8;
  int c0 = wv * 32;
  f32x4 acc[8][2] = {};
#pragma unroll
  for (int ks = 0; ks < 4; ++ks) {
    int kb = ks * 32 + lk;
    bf16x8 bfr0 = *(const bf16x8*)&Wt[(size_t)(c0 + (l & 15)) * 128 + kb];
    bf16x8 bfr1 = *(const bf16x8*)&Wt[(size_t)(c0 + 16 + (l & 15)) * 128 + kb];
#pragma unroll
    for (int rt = 0; rt < 8; ++rt) {
      int row = r0 + rt * 16 + (l & 15);
      row = row < NN ? row : NN - 1;
      bf16x8 afr = *(const bf16x8*)&Ab[(size_t)row * 128 + kb];
      acc[rt][0] = __builtin_amdgcn_mfma_f32_16x16x32_bf16(afr, bfr0, acc[rt][0], 0, 0, 0);
      acc[rt][1] = __builtin_amdgcn_mfma_f32_16x16x32_bf16(afr, bfr1, acc[rt][1], 0, 0, 0);
    }
  }
  // C/D: col = lane&15, row = (lane>>4)*4 + reg -> LDS tile
#pragma unroll
  for (int rt = 0; rt < 8; ++rt) {
#pragma unroll
    for (int j = 0; j < 4; ++j) {
      int lr = rt * 16 + (l >> 4) * 4 + j;
      cl[lr][c0 + (l & 15)] = f2bf(acc[rt][0][j]);
      cl[lr][c0 + 16 + (l & 15)] = f2bf(acc[rt][1][j]);
    }
  }
  __syncthreads();
  // coalesced C store: row = t>>1, piece p = t&1; 8 uint4 per thread
  int row = t >> 1;
  int grow = r0 + row;
  int p = t & 1;
  if (grow < NN) {
    uint4* dst = (uint4*)&xpb[(size_t)grow * 128];
#pragma unroll
    for (int q = 0; q < 8; ++q)
      dst[q * 2 + p] = *(uint4*)&cl[row][(q * 2 + p) * 8];
  }
  // a_s/a_d: 512 (row,head) dots over 256 threads -> 2 each
  int row2 = t >> 2;
  int hh = t & 3;
  int hc = hh * 32;
#pragma unroll
  for (int half = 0; half < 2; ++half) {
    int rr = row2 + half * 64;
    int gr = r0 + rr;
    float ps = 0.f, pd = 0.f;
#pragma unroll
    for (int q = 0; q < 4; ++q) {
      uint4 u = *(uint4*)&cl[rr][hc + q * 8];
      const unsigned short* us = (const unsigned short*)&u;
#pragma unroll
      for (int k = 0; k < 8; ++k) {
        float xv = bf2f(us[k]);
        ps += xv * swS[hc + q * 8 + k];
        pd += xv * dwS[hc + q * 8 + k];
      }
    }
    if (gr < NN) {
      a_s[(size_t)gr * 4 + hh] = ps;
      a_d[(size_t)gr * 4 + hh] = pd;
    }
  }
}

// 1 wave/node. 16-edge batches: lane (q=lane&15, h=lane>>4) computes ONE
// (edge,head) weight. srcv is identical across the 4 head groups ->
// distribute via readlane (SGPR, scalar gather base); w via __shfl.
// Early-exit tail at 4-edge granularity (wave-uniform branch).
__global__ __launch_bounds__(256) void k_aggr(const unsigned short* __restrict__ xpb,
                                              const unsigned short* __restrict__ ae_l,
                                              const unsigned short* __restrict__ aeself_l,
                                              const float* __restrict__ a_s,
                                              const float* __restrict__ a_d,
                                              const int* __restrict__ csr_src,
                                              const int* __restrict__ offs,
                                              const float* __restrict__ b_l,
                                              unsigned short* __restrict__ hout) {
  int node = blockIdx.x * 4 + (threadIdx.x >> 6);
  if (node >= NN) return;
  int lane = threadIdx.x & 63;
  int q = lane & 15;
  int h = lane >> 4;
  int base = lane & 48;  // 16*h
  const ushort2* xp2 = (const ushort2*)xpb;
  int s = offs[node], e = offs[node + 1];
  float ad = a_d[(size_t)node * 4 + h];
  float vs = a_s[(size_t)node * 4 + h] + ad + bf2f(aeself_l[(size_t)node * 4 + h]);
  vs = vs > 0.f ? vs : NEG * vs;
  float es = __expf(fminf(vs, 60.f));
  ushort2 xs = xp2[(size_t)node * 64 + lane];
  float acc0 = es * bf2f(xs.x), acc1 = es * bf2f(xs.y);
  float den = es;
  for (int i = s; i < e; i += 16) {
    int cnt = e - i;
    int lim = cnt < 16 ? cnt : 16;
    int srcv = 0;
    float w = 0.f;
    if (q < cnt) {
      srcv = csr_src[i + q];
      float a = a_s[(size_t)srcv * 4 + h] + ad + bf2f(ae_l[(size_t)(i + q) * 4 + h]);
      a = a > 0.f ? a : NEG * a;
      w = __expf(fminf(a, 60.f));
    }
    for (int qq4 = 0; qq4 < lim; qq4 += 4) {
#pragma unroll
      for (int u = 0; u < 4; ++u) {
        int qq = qq4 + u;
        int sq = __builtin_amdgcn_readlane(srcv, qq);   // wave-uniform (SGPR)
        float wq = __shfl(w, base | qq);
        ushort2 xq = xp2[(size_t)sq * 64 + lane];
        den += wq;
        acc0 += wq * bf2f(xq.x);
        acc1 += wq * bf2f(xq.y);
      }
    }
  }
  float2 b2 = ((const float2*)b_l)[lane];
  float inv = 1.0f / (den + 1e-16f);
  float o0 = fmaxf(acc0 * inv + b2.x, 0.f);
  float o1 = fmaxf(acc1 * inv + b2.y, 0.f);
  ushort2 ho;
  ho.x = f2bf(o0); ho.y = f2bf(o1);
  ((ushort2*)hout)[(size_t)node * 64 + lane] = ho;
}

// out = relu([x, h] @ Wout + bout) — LDS-staged Wout; h is bf16.
__global__ __launch_bounds__(256) void k_final(const float* __restrict__ x,
                                               const unsigned short* __restrict__ h,
                                               const float* __restrict__ Wout, const float* __restrict__ bout,
                                               float* __restrict__ out) {
  __shared__ float4 wlds[2048];
  int t = threadIdx.x;
#pragma unroll
  for (int i = 0; i < 8; ++i) wlds[t + i * 256] = ((const float4*)Wout)[t + i * 256];
  __syncthreads();
  int tx = t & 7;
  int ty = t >> 3;
  int row0 = blockIdx.x * 64 + ty;
  int row1 = row0 + 32;
  bool v0 = row0 < NN, v1 = row1 < NN;
  const float4* x4 = (const float4*)x;
  const ushort4* h4 = (const ushort4*)h;
  float acc[2][4] = {};
  const float4 z = make_float4(0.f, 0.f, 0.f, 0.f);
#pragma unroll 4
  for (int k4 = 0; k4 < 32; ++k4) {
    float4 a0 = v0 ? x4[(size_t)row0 * 32 + k4] : z;
    float4 a1 = v1 ? x4[(size_t)row1 * 32 + k4] : z;
    float av0[4] = {a0.x, a0.y, a0.z, a0.w};
    float av1[4] = {a1.x, a1.y, a1.z, a1.w};
#pragma unroll
    for (int kk = 0; kk < 4; ++kk) {
      float4 w = wlds[(k4 * 4 + kk) * 8 + tx];
      acc[0][0] += av0[kk] * w.x; acc[0][1] += av0[kk] * w.y;
      acc[0][2] += av0[kk] * w.z; acc[0][3] += av0[kk] * w.w;
      acc[1][0] += av1[kk] * w.x; acc[1][1] += av1[kk] * w.y;
      acc[1][2] += av1[kk] * w.z; acc[1][3] += av1[kk] * w.w;
    }
  }
#pragma unroll 4
  for (int k4 = 0; k4 < 32; ++k4) {
    ushort4 u0 = v0 ? h4[(size_t)row0 * 32 + k4] : make_ushort4(0, 0, 0, 0);
    ushort4 u1 = v1 ? h4[(size_t)row1 * 32 + k4] : make_ushort4(0, 0, 0, 0);
    float av0[4] = {bf2f(u0.x), bf2f(u0.y), bf2f(u0.z), bf2f(u0.w)};
    float av1[4] = {bf2f(u1.x), bf2f(u1.y), bf2f(u1.z), bf2f(u1.w)};
#pragma unroll
    for (int kk = 0; kk < 4; ++kk) {
      float4 w = wlds[(128 + k4 * 4 + kk) * 8 + tx];
      acc[0][0] += av0[kk] * w.x; acc[0][1] += av0[kk] * w.y;
      acc[0][2] += av0[kk] * w.z; acc[0][3] += av0[kk] * w.w;
      acc[1][0] += av1[kk] * w.x; acc[1][1] += av1[kk] * w.y;
      acc[1][2] += av1[kk] * w.z; acc[1][3] += av1[kk] * w.w;
    }
  }
  float4 b4 = ((const float4*)bout)[tx];
  if (v0) {
    float4 o = make_float4(fmaxf(acc[0][0] + b4.x, 0.f), fmaxf(acc[0][1] + b4.y, 0.f),
                           fmaxf(acc[0][2] + b4.z, 0.f), fmaxf(acc[0][3] + b4.w, 0.f));
    ((float4*)out)[(size_t)row0 * 8 + tx] = o;
  }
  if (v1) {
    float4 o = make_float4(fmaxf(acc[1][0] + b4.x, 0.f), fmaxf(acc[1][1] + b4.y, 0.f),
                           fmaxf(acc[1][2] + b4.z, 0.f), fmaxf(acc[1][3] + b4.w, 0.f));
    ((float4*)out)[(size_t)row1 * 8 + tx] = o;
  }
}

extern "C" void kernel_launch(void* const* d_in, const int* in_sizes, int n_in,
                              void* d_out, int out_size, void* d_ws, size_t ws_size,
                              hipStream_t stream) {
  const float* x        = (const float*)d_in[0];
  const int*   eidx     = (const int*)d_in[1];
  const float* eattr    = (const float*)d_in[2];
  const float* W        = (const float*)d_in[3];
  const float* att_src  = (const float*)d_in[4];
  const float* att_dst  = (const float*)d_in[5];
  const float* We       = (const float*)d_in[6];
  const float* att_edge = (const float*)d_in[7];
  const float* b        = (const float*)d_in[8];
  const float* Wout     = (const float*)d_in[9];
  const float* bout     = (const float*)d_in[10];
  float* out = (float*)d_out;

  const int* esrc = eidx;
  const int* edst = eidx + NE;

  size_t off = 0;
  auto carve = [&](size_t bytes) {
    void* p = (char*)d_ws + off;
    off += (bytes + 255) & ~(size_t)255;
    return p;
  };
  unsigned short* h_buf   = (unsigned short*)carve((size_t)NN * HC * 2);  // bf16(x) for layer 0
  unsigned short* xpb     = (unsigned short*)carve((size_t)NN * HC * 2);
  unsigned short* Wt      = (unsigned short*)carve((size_t)DEPTH * NF * HC * 2);
  unsigned short* ae_csr  = (unsigned short*)carve((size_t)DEPTH * NE * NH * 2);
  unsigned short* ae_self = (unsigned short*)carve((size_t)DEPTH * NN * NH * 2);
  float* a_s   = (float*)carve((size_t)NN * NH * 4);
  float* a_d   = (float*)carve((size_t)NN * NH * 4);
  float* weff  = (float*)carve((size_t)DEPTH * BF * NH * 4);
  int* deg  = (int*)carve((size_t)NN * 4);
  int* offs = (int*)carve((size_t)(NN + 1) * 4);
  int* cur  = (int*)carve((size_t)NN * 4);
  int2* staging = (int2*)carve((size_t)NE * 8);
  int* csr_eid = (int*)carve((size_t)NE * 4);
  int* csr_src = (int*)carve((size_t)NE * 4);
  int* pcnt  = (int*)carve((size_t)NPART * 4);
  int* pbase = (int*)carve((size_t)(NPART + 1) * 4);
  int* pcur  = (int*)carve((size_t)NPART * 4);
  int* bsum = (int*)carve(1024);

  const int nbN = (NN + 255) / 256;
  const int nbE = (NE + 255) / 256;
  const int nbP = (NE + PTILE - 1) / PTILE;

  hipMemsetAsync(deg, 0, (size_t)NN * 4, stream);
  hipMemsetAsync(pcnt, 0, (size_t)NPART * 4, stream);
  k_cnt0<<<nbP, 256, 0, stream>>>(edst, deg, pcnt);
  k_partial<<<nbN, 256, 0, stream>>>(deg, bsum);
  k_scan_top<<<1, 64, 0, stream>>>(bsum, nbN);
  k_scan_write<<<nbN, 256, 0, stream>>>(deg, bsum, offs, cur);
  k_pscan<<<1, NPART, 0, stream>>>(pcnt, pbase, pcur);
  k_p1<<<nbP, 256, 0, stream>>>(edst, pcur, staging);
  k_p2<<<NPART, 256, 0, stream>>>(staging, pbase, cur, csr_eid);
  k_weff<<<1, 320, 0, stream>>>(We, att_edge, weff);
  k_aeprep<<<nbE, 256, 0, stream>>>(csr_eid, esrc, eattr, weff, ae_csr, csr_src);
  k_aeself<<<(NN * DEPTH + 255) / 256, 256, 0, stream>>>(ae_csr, offs, ae_self);
  k_x2bf<<<(NN * 32 + 255) / 256, 256, 0, stream>>>(x, h_buf);
  k_wprep<<<(DEPTH * NF * HC + 255) / 256, 256, 0, stream>>>(W, Wt);

  for (int l = 0; l < DEPTH; ++l) {
    k_gemm_mfma<<<(NN + 127) / 128, 256, 0, stream>>>(h_buf, Wt + (size_t)l * NF * HC,
                                                      att_src + (size_t)l * NH * CC,
                                                      att_dst + (size_t)l * NH * CC,
                                                      xpb, a_s, a_d);
    k_aggr<<<(NN + 3) / 4, 256, 0, stream>>>(xpb,
                                             ae_csr + (size_t)l * NE * NH,
                                             ae_self + (size_t)l * NN * NH,
                                             a_s, a_d, csr_src, offs,
                                             b + (size_t)l * HC, h_buf);
  }
  k_final<<<(NN + 63) / 64, 256, 0, stream>>>(x, h_buf, Wout, bout, out);
}

// Round 14
// 475.495 us; speedup vs baseline: 1.0145x; 1.0145x over previous
//
#include <hip/hip_runtime.h>

#define NN 50000
#define NE 800000
#define NF 128
#define BF 16
#define NH 4
#define HC 128
#define CC 32
#define DEPTH 5
#define NEG 0.2f
#define NPART 256
#define PTILE 4096

typedef __attribute__((ext_vector_type(8))) short bf16x8;
typedef __attribute__((ext_vector_type(4))) float f32x4;

__device__ inline unsigned short f2bf(float f) {
  union { float f; unsigned u; } v; v.f = f;
  unsigned r = v.u + 0x7fff + ((v.u >> 16) & 1);
  return (unsigned short)(r >> 16);
}
__device__ inline float bf2f(unsigned short u) {
  union { unsigned u; float f; } v; v.u = (unsigned)u << 16; return v.f;
}

// ---------------- CSR build ----------------
// fused: per-node degree count + per-partition histogram, one edst pass
__global__ __launch_bounds__(256) void k_cnt0(const int* __restrict__ edst,
                                              int* __restrict__ deg,
                                              int* __restrict__ pcnt) {
  __shared__ int lc[NPART];
  int t = threadIdx.x;
  lc[t] = 0;
  __syncthreads();
  int base = blockIdx.x * PTILE;
#pragma unroll
  for (int j = 0; j < PTILE / 256; ++j) {
    int e = base + t + j * 256;
    if (e < NE) {
      int d = edst[e];
      atomicAdd(&deg[d], 1);
      atomicAdd(&lc[d >> 8], 1);
    }
  }
  __syncthreads();
  if (lc[t]) atomicAdd(&pcnt[t], lc[t]);
}

__global__ void k_partial(const int* __restrict__ deg, int* __restrict__ bsum) {
  __shared__ int s[256];
  int t = threadIdx.x;
  int i = blockIdx.x * 256 + t;
  s[t] = (i < NN) ? deg[i] : 0;
  __syncthreads();
  for (int d = 128; d > 0; d >>= 1) {
    if (t < d) s[t] += s[t + d];
    __syncthreads();
  }
  if (t == 0) bsum[blockIdx.x] = s[0];
}

__global__ void k_scan_top(int* __restrict__ bsum, int nb) {
  if (threadIdx.x == 0 && blockIdx.x == 0) {
    int run = 0;
    for (int i = 0; i < nb; ++i) { int v = bsum[i]; bsum[i] = run; run += v; }
  }
}

__global__ void k_scan_write(const int* __restrict__ deg, const int* __restrict__ bsum,
                             int* __restrict__ offs, int* __restrict__ cur) {
  __shared__ int s[256];
  int t = threadIdx.x;
  int i = blockIdx.x * 256 + t;
  int v = (i < NN) ? deg[i] : 0;
  s[t] = v;
  __syncthreads();
  for (int d = 1; d < 256; d <<= 1) {
    int x = (t >= d) ? s[t - d] : 0;
    __syncthreads();
    s[t] += x;
    __syncthreads();
  }
  if (i < NN) {
    int o = bsum[blockIdx.x] + s[t] - v;
    offs[i] = o;
    cur[i] = o;
  }
  if (i == 0) offs[NN] = NE;
}

__global__ void k_pscan(const int* __restrict__ pcnt, int* __restrict__ pbase,
                        int* __restrict__ pcur) {
  __shared__ int s[NPART];
  int t = threadIdx.x;
  int v = pcnt[t];
  s[t] = v;
  __syncthreads();
  for (int d = 1; d < NPART; d <<= 1) {
    int x = (t >= d) ? s[t - d] : 0;
    __syncthreads();
    s[t] += x;
    __syncthreads();
  }
  int ex = s[t] - v;
  pbase[t] = ex;
  pcur[t] = ex;
  if (t == NPART - 1) pbase[NPART] = s[NPART - 1];
}

__global__ __launch_bounds__(256) void k_p1(const int* __restrict__ edst,
                                            int* __restrict__ pcur,
                                            int2* __restrict__ staging) {
  __shared__ int lc[NPART];
  __shared__ int lbase[NPART];
  __shared__ int lrank[NPART];
  int t = threadIdx.x;
  lc[t] = 0;
  __syncthreads();
  int base = blockIdx.x * PTILE;
  int myd[PTILE / 256];
#pragma unroll
  for (int j = 0; j < PTILE / 256; ++j) {
    int e = base + t + j * 256;
    int d = (e < NE) ? edst[e] : -1;
    myd[j] = d;
    if (d >= 0) atomicAdd(&lc[d >> 8], 1);
  }
  __syncthreads();
  if (lc[t]) lbase[t] = atomicAdd(&pcur[t], lc[t]);
  lrank[t] = 0;
  __syncthreads();
#pragma unroll
  for (int j = 0; j < PTILE / 256; ++j) {
    int d = myd[j];
    if (d >= 0) {
      int p = d >> 8;
      int r = atomicAdd(&lrank[p], 1);
      staging[lbase[p] + r] = make_int2(base + t + j * 256, d);
    }
  }
}

__global__ __launch_bounds__(256) void k_p2(const int2* __restrict__ staging,
                                            const int* __restrict__ pbase,
                                            int* __restrict__ cur,
                                            int* __restrict__ csr_eid) {
  int p = blockIdx.x;
  int s = pbase[p], e = pbase[p + 1];
  for (int i = s + threadIdx.x; i < e; i += 256) {
    int2 st = staging[i];
    int slot = atomicAdd(&cur[st.y], 1);
    csr_eid[slot] = st.x;
  }
}

// ---------------- prep kernels (once) ----------------
__global__ void k_weff(const float* __restrict__ We, const float* __restrict__ ae,
                       float* __restrict__ weff) {
  int idx = threadIdx.x;
  if (idx >= DEPTH * BF * NH) return;
  int l = idx / (BF * NH);
  int r = idx - l * (BF * NH);
  int f = r >> 2, h = r & 3;
  const float* We_l = We + (size_t)l * BF * HC;
  const float* ae_l = ae + (size_t)l * NH * CC;
  float acc = 0.f;
  for (int c = 0; c < CC; ++c) acc += We_l[f * HC + h * CC + c] * ae_l[h * CC + c];
  weff[idx] = acc;
}

__global__ __launch_bounds__(256) void k_aeprep(const int* __restrict__ csr_eid,
                                                const int* __restrict__ esrc,
                                                const float* __restrict__ eattr,
                                                const float* __restrict__ weff,
                                                unsigned short* __restrict__ ae_csr,
                                                int* __restrict__ csr_src) {
  __shared__ float sw[DEPTH * BF * NH];
  int t = threadIdx.x;
  if (t < DEPTH * BF * NH) sw[t] = weff[t];
  __syncthreads();
  int i = blockIdx.x * 256 + t;
  if (i >= NE) return;
  int eid = csr_eid[i];
  csr_src[i] = esrc[eid];
  float at[16];
  const float4* ar = (const float4*)(eattr + (size_t)eid * BF);
#pragma unroll
  for (int q = 0; q < 4; ++q) {
    float4 v = ar[q];
    at[q * 4] = v.x; at[q * 4 + 1] = v.y; at[q * 4 + 2] = v.z; at[q * 4 + 3] = v.w;
  }
#pragma unroll
  for (int l = 0; l < DEPTH; ++l) {
    float a0 = 0.f, a1 = 0.f, a2 = 0.f, a3 = 0.f;
#pragma unroll
    for (int f = 0; f < BF; ++f) {
      float av = at[f];
      const float* wf = &sw[(l * BF + f) * NH];
      a0 += av * wf[0]; a1 += av * wf[1]; a2 += av * wf[2]; a3 += av * wf[3];
    }
    ushort4 u;
    u.x = f2bf(a0); u.y = f2bf(a1); u.z = f2bf(a2); u.w = f2bf(a3);
    ((ushort4*)ae_csr)[(size_t)l * NE + i] = u;
  }
}

__global__ void k_aeself(const unsigned short* __restrict__ ae_csr,
                         const int* __restrict__ offs,
                         unsigned short* __restrict__ ae_self) {
  int idx = blockIdx.x * 256 + threadIdx.x;
  if (idx >= NN * DEPTH) return;
  int l = idx / NN, n = idx - l * NN;
  int s = offs[n], e = offs[n + 1];
  const ushort4* base = (const ushort4*)ae_csr + (size_t)l * NE;
  float a0 = 0.f, a1 = 0.f, a2 = 0.f, a3 = 0.f;
  for (int i = s; i < e; ++i) {
    ushort4 u = base[i];
    a0 += bf2f(u.x); a1 += bf2f(u.y); a2 += bf2f(u.z); a3 += bf2f(u.w);
  }
  float inv = 1.0f / fmaxf((float)(e - s), 1.0f);
  ushort4 o;
  o.x = f2bf(a0 * inv); o.y = f2bf(a1 * inv); o.z = f2bf(a2 * inv); o.w = f2bf(a3 * inv);
  ((ushort4*)ae_self)[(size_t)l * NN + n] = o;
}

__global__ void k_x2bf(const float* __restrict__ x, unsigned short* __restrict__ xb) {
  int i = blockIdx.x * 256 + threadIdx.x;
  if (i >= NN * 32) return;
  float4 v = ((const float4*)x)[i];
  ushort4 u;
  u.x = f2bf(v.x); u.y = f2bf(v.y); u.z = f2bf(v.z); u.w = f2bf(v.w);
  ((ushort4*)xb)[i] = u;
}

__global__ void k_wprep(const float* __restrict__ W, unsigned short* __restrict__ Wt) {
  int idx = blockIdx.x * 256 + threadIdx.x;
  if (idx >= DEPTH * NF * HC) return;
  int l = idx >> 14;
  int rem = idx & 16383;
  int n = rem >> 7, k = rem & 127;
  Wt[(size_t)l * 16384 + (size_t)n * 128 + k] = f2bf(W[(size_t)l * 16384 + (size_t)k * 128 + n]);
}

// ---------------- per-layer kernels ----------------
// xp = A @ W via bf16 MFMA; 128-row x 128-col block, 4 waves (wave = 32-col strip).
// LDS C-tile epilogue: coalesced uint4 stores + a_s/a_d dots.
__global__ __launch_bounds__(256) void k_gemm_mfma(const unsigned short* __restrict__ Ab,
                                                   const unsigned short* __restrict__ Wt,
                                                   const float* __restrict__ as_w,
                                                   const float* __restrict__ ad_w,
                                                   unsigned short* __restrict__ xpb,
                                                   float* __restrict__ a_s,
                                                   float* __restrict__ a_d) {
  __shared__ unsigned short cl[128][144];
  __shared__ float swS[128], dwS[128];
  int t = threadIdx.x;
  if (t < 128) { swS[t] = as_w[t]; dwS[t] = ad_w[t]; }
  int wv = t >> 6;
  int l = t & 63;
  int r0 = blockIdx.x * 128;
  int lk = (l >> 4) * 8;
  int c0 = wv * 32;
  f32x4 acc[8][2] = {};
#pragma unroll
  for (int ks = 0; ks < 4; ++ks) {
    int kb = ks * 32 + lk;
    bf16x8 bfr0 = *(const bf16x8*)&Wt[(size_t)(c0 + (l & 15)) * 128 + kb];
    bf16x8 bfr1 = *(const bf16x8*)&Wt[(size_t)(c0 + 16 + (l & 15)) * 128 + kb];
#pragma unroll
    for (int rt = 0; rt < 8; ++rt) {
      int row = r0 + rt * 16 + (l & 15);
      row = row < NN ? row : NN - 1;
      bf16x8 afr = *(const bf16x8*)&Ab[(size_t)row * 128 + kb];
      acc[rt][0] = __builtin_amdgcn_mfma_f32_16x16x32_bf16(afr, bfr0, acc[rt][0], 0, 0, 0);
      acc[rt][1] = __builtin_amdgcn_mfma_f32_16x16x32_bf16(afr, bfr1, acc[rt][1], 0, 0, 0);
    }
  }
  // C/D: col = lane&15, row = (lane>>4)*4 + reg -> LDS tile
#pragma unroll
  for (int rt = 0; rt < 8; ++rt) {
#pragma unroll
    for (int j = 0; j < 4; ++j) {
      int lr = rt * 16 + (l >> 4) * 4 + j;
      cl[lr][c0 + (l & 15)] = f2bf(acc[rt][0][j]);
      cl[lr][c0 + 16 + (l & 15)] = f2bf(acc[rt][1][j]);
    }
  }
  __syncthreads();
  // coalesced C store: row = t>>1, piece p = t&1; 8 uint4 per thread
  int row = t >> 1;
  int grow = r0 + row;
  int p = t & 1;
  if (grow < NN) {
    uint4* dst = (uint4*)&xpb[(size_t)grow * 128];
#pragma unroll
    for (int q = 0; q < 8; ++q)
      dst[q * 2 + p] = *(uint4*)&cl[row][(q * 2 + p) * 8];
  }
  // a_s/a_d: 512 (row,head) dots over 256 threads -> 2 each
  int row2 = t >> 2;
  int hh = t & 3;
  int hc = hh * 32;
#pragma unroll
  for (int half = 0; half < 2; ++half) {
    int rr = row2 + half * 64;
    int gr = r0 + rr;
    float ps = 0.f, pd = 0.f;
#pragma unroll
    for (int q = 0; q < 4; ++q) {
      uint4 u = *(uint4*)&cl[rr][hc + q * 8];
      const unsigned short* us = (const unsigned short*)&u;
#pragma unroll
      for (int k = 0; k < 8; ++k) {
        float xv = bf2f(us[k]);
        ps += xv * swS[hc + q * 8 + k];
        pd += xv * dwS[hc + q * 8 + k];
      }
    }
    if (gr < NN) {
      a_s[(size_t)gr * 4 + hh] = ps;
      a_d[(size_t)gr * 4 + hh] = pd;
    }
  }
}

// 1 wave/node. 16-edge batches: lane (q=lane&15, h=lane>>4) computes ONE
// (edge,head) weight; weights+srcs distributed via __shfl. No-max exp (clamped).
__global__ __launch_bounds__(256) void k_aggr(const unsigned short* __restrict__ xpb,
                                              const unsigned short* __restrict__ ae_l,
                                              const unsigned short* __restrict__ aeself_l,
                                              const float* __restrict__ a_s,
                                              const float* __restrict__ a_d,
                                              const int* __restrict__ csr_src,
                                              const int* __restrict__ offs,
                                              const float* __restrict__ b_l,
                                              unsigned short* __restrict__ hout) {
  int node = blockIdx.x * 4 + (threadIdx.x >> 6);
  if (node >= NN) return;
  int lane = threadIdx.x & 63;
  int q = lane & 15;
  int h = lane >> 4;
  int base = lane & 48;  // 16*h
  const ushort2* xp2 = (const ushort2*)xpb;
  int s = offs[node], e = offs[node + 1];
  float ad = a_d[(size_t)node * 4 + h];
  float vs = a_s[(size_t)node * 4 + h] + ad + bf2f(aeself_l[(size_t)node * 4 + h]);
  vs = vs > 0.f ? vs : NEG * vs;
  float es = __expf(fminf(vs, 60.f));
  ushort2 xs = xp2[(size_t)node * 64 + lane];
  float acc0 = es * bf2f(xs.x), acc1 = es * bf2f(xs.y);
  float den = es;
  for (int i = s; i < e; i += 16) {
    int cnt = e - i;
    int srcv = 0;
    float w = 0.f;
    if (q < cnt) {
      srcv = csr_src[i + q];
      float a = a_s[(size_t)srcv * 4 + h] + ad + bf2f(ae_l[(size_t)(i + q) * 4 + h]);
      a = a > 0.f ? a : NEG * a;
      w = __expf(fminf(a, 60.f));
    }
#pragma unroll 8
    for (int qq = 0; qq < 16; ++qq) {
      int sq = __shfl(srcv, base | qq);
      float wq = __shfl(w, base | qq);
      ushort2 xq = xp2[(size_t)sq * 64 + lane];
      den += wq;
      acc0 += wq * bf2f(xq.x);
      acc1 += wq * bf2f(xq.y);
    }
  }
  float2 b2 = ((const float2*)b_l)[lane];
  float inv = 1.0f / (den + 1e-16f);
  float o0 = fmaxf(acc0 * inv + b2.x, 0.f);
  float o1 = fmaxf(acc1 * inv + b2.y, 0.f);
  ushort2 ho;
  ho.x = f2bf(o0); ho.y = f2bf(o1);
  ((ushort2*)hout)[(size_t)node * 64 + lane] = ho;
}

// out = relu([x, h] @ Wout + bout) — LDS-staged Wout; h is bf16.
__global__ __launch_bounds__(256) void k_final(const float* __restrict__ x,
                                               const unsigned short* __restrict__ h,
                                               const float* __restrict__ Wout, const float* __restrict__ bout,
                                               float* __restrict__ out) {
  __shared__ float4 wlds[2048];
  int t = threadIdx.x;
#pragma unroll
  for (int i = 0; i < 8; ++i) wlds[t + i * 256] = ((const float4*)Wout)[t + i * 256];
  __syncthreads();
  int tx = t & 7;
  int ty = t >> 3;
  int row0 = blockIdx.x * 64 + ty;
  int row1 = row0 + 32;
  bool v0 = row0 < NN, v1 = row1 < NN;
  const float4* x4 = (const float4*)x;
  const ushort4* h4 = (const ushort4*)h;
  float acc[2][4] = {};
  const float4 z = make_float4(0.f, 0.f, 0.f, 0.f);
#pragma unroll 4
  for (int k4 = 0; k4 < 32; ++k4) {
    float4 a0 = v0 ? x4[(size_t)row0 * 32 + k4] : z;
    float4 a1 = v1 ? x4[(size_t)row1 * 32 + k4] : z;
    float av0[4] = {a0.x, a0.y, a0.z, a0.w};
    float av1[4] = {a1.x, a1.y, a1.z, a1.w};
#pragma unroll
    for (int kk = 0; kk < 4; ++kk) {
      float4 w = wlds[(k4 * 4 + kk) * 8 + tx];
      acc[0][0] += av0[kk] * w.x; acc[0][1] += av0[kk] * w.y;
      acc[0][2] += av0[kk] * w.z; acc[0][3] += av0[kk] * w.w;
      acc[1][0] += av1[kk] * w.x; acc[1][1] += av1[kk] * w.y;
      acc[1][2] += av1[kk] * w.z; acc[1][3] += av1[kk] * w.w;
    }
  }
#pragma unroll 4
  for (int k4 = 0; k4 < 32; ++k4) {
    ushort4 u0 = v0 ? h4[(size_t)row0 * 32 + k4] : make_ushort4(0, 0, 0, 0);
    ushort4 u1 = v1 ? h4[(size_t)row1 * 32 + k4] : make_ushort4(0, 0, 0, 0);
    float av0[4] = {bf2f(u0.x), bf2f(u0.y), bf2f(u0.z), bf2f(u0.w)};
    float av1[4] = {bf2f(u1.x), bf2f(u1.y), bf2f(u1.z), bf2f(u1.w)};
#pragma unroll
    for (int kk = 0; kk < 4; ++kk) {
      float4 w = wlds[(128 + k4 * 4 + kk) * 8 + tx];
      acc[0][0] += av0[kk] * w.x; acc[0][1] += av0[kk] * w.y;
      acc[0][2] += av0[kk] * w.z; acc[0][3] += av0[kk] * w.w;
      acc[1][0] += av1[kk] * w.x; acc[1][1] += av1[kk] * w.y;
      acc[1][2] += av1[kk] * w.z; acc[1][3] += av1[kk] * w.w;
    }
  }
  float4 b4 = ((const float4*)bout)[tx];
  if (v0) {
    float4 o = make_float4(fmaxf(acc[0][0] + b4.x, 0.f), fmaxf(acc[0][1] + b4.y, 0.f),
                           fmaxf(acc[0][2] + b4.z, 0.f), fmaxf(acc[0][3] + b4.w, 0.f));
    ((float4*)out)[(size_t)row0 * 8 + tx] = o;
  }
  if (v1) {
    float4 o = make_float4(fmaxf(acc[1][0] + b4.x, 0.f), fmaxf(acc[1][1] + b4.y, 0.f),
                           fmaxf(acc[1][2] + b4.z, 0.f), fmaxf(acc[1][3] + b4.w, 0.f));
    ((float4*)out)[(size_t)row1 * 8 + tx] = o;
  }
}

extern "C" void kernel_launch(void* const* d_in, const int* in_sizes, int n_in,
                              void* d_out, int out_size, void* d_ws, size_t ws_size,
                              hipStream_t stream) {
  const float* x        = (const float*)d_in[0];
  const int*   eidx     = (const int*)d_in[1];
  const float* eattr    = (const float*)d_in[2];
  const float* W        = (const float*)d_in[3];
  const float* att_src  = (const float*)d_in[4];
  const float* att_dst  = (const float*)d_in[5];
  const float* We       = (const float*)d_in[6];
  const float* att_edge = (const float*)d_in[7];
  const float* b        = (const float*)d_in[8];
  const float* Wout     = (const float*)d_in[9];
  const float* bout     = (const float*)d_in[10];
  float* out = (float*)d_out;

  const int* esrc = eidx;
  const int* edst = eidx + NE;

  size_t off = 0;
  auto carve = [&](size_t bytes) {
    void* p = (char*)d_ws + off;
    off += (bytes + 255) & ~(size_t)255;
    return p;
  };
  unsigned short* h_buf   = (unsigned short*)carve((size_t)NN * HC * 2);  // bf16(x) for layer 0
  unsigned short* xpb     = (unsigned short*)carve((size_t)NN * HC * 2);
  unsigned short* Wt      = (unsigned short*)carve((size_t)DEPTH * NF * HC * 2);
  unsigned short* ae_csr  = (unsigned short*)carve((size_t)DEPTH * NE * NH * 2);
  unsigned short* ae_self = (unsigned short*)carve((size_t)DEPTH * NN * NH * 2);
  float* a_s   = (float*)carve((size_t)NN * NH * 4);
  float* a_d   = (float*)carve((size_t)NN * NH * 4);
  float* weff  = (float*)carve((size_t)DEPTH * BF * NH * 4);
  int* deg  = (int*)carve((size_t)NN * 4);
  int* offs = (int*)carve((size_t)(NN + 1) * 4);
  int* cur  = (int*)carve((size_t)NN * 4);
  int2* staging = (int2*)carve((size_t)NE * 8);
  int* csr_eid = (int*)carve((size_t)NE * 4);
  int* csr_src = (int*)carve((size_t)NE * 4);
  int* pcnt  = (int*)carve((size_t)NPART * 4);
  int* pbase = (int*)carve((size_t)(NPART + 1) * 4);
  int* pcur  = (int*)carve((size_t)NPART * 4);
  int* bsum = (int*)carve(1024);

  const int nbN = (NN + 255) / 256;
  const int nbE = (NE + 255) / 256;
  const int nbP = (NE + PTILE - 1) / PTILE;

  hipMemsetAsync(deg, 0, (size_t)NN * 4, stream);
  hipMemsetAsync(pcnt, 0, (size_t)NPART * 4, stream);
  k_cnt0<<<nbP, 256, 0, stream>>>(edst, deg, pcnt);
  k_partial<<<nbN, 256, 0, stream>>>(deg, bsum);
  k_scan_top<<<1, 64, 0, stream>>>(bsum, nbN);
  k_scan_write<<<nbN, 256, 0, stream>>>(deg, bsum, offs, cur);
  k_pscan<<<1, NPART, 0, stream>>>(pcnt, pbase, pcur);
  k_p1<<<nbP, 256, 0, stream>>>(edst, pcur, staging);
  k_p2<<<NPART, 256, 0, stream>>>(staging, pbase, cur, csr_eid);
  k_weff<<<1, 320, 0, stream>>>(We, att_edge, weff);
  k_aeprep<<<nbE, 256, 0, stream>>>(csr_eid, esrc, eattr, weff, ae_csr, csr_src);
  k_aeself<<<(NN * DEPTH + 255) / 256, 256, 0, stream>>>(ae_csr, offs, ae_self);
  k_x2bf<<<(NN * 32 + 255) / 256, 256, 0, stream>>>(x, h_buf);
  k_wprep<<<(DEPTH * NF * HC + 255) / 256, 256, 0, stream>>>(W, Wt);

  for (int l = 0; l < DEPTH; ++l) {
    k_gemm_mfma<<<(NN + 127) / 128, 256, 0, stream>>>(h_buf, Wt + (size_t)l * NF * HC,
                                                      att_src + (size_t)l * NH * CC,
                                                      att_dst + (size_t)l * NH * CC,
                                                      xpb, a_s, a_d);
    k_aggr<<<(NN + 3) / 4, 256, 0, stream>>>(xpb,
                                             ae_csr + (size_t)l * NE * NH,
                                             ae_self + (size_t)l * NN * NH,
                                             a_s, a_d, csr_src, offs,
                                             b + (size_t)l * HC, h_buf);
  }
  k_final<<<(NN + 63) / 64, 256, 0, stream>>>(x, h_buf, Wout, bout, out);
}

// Round 15
// 420.861 us; speedup vs baseline: 1.1462x; 1.1298x over previous
//
#include <hip/hip_runtime.h>

#define NN 50000
#define NE 800000
#define NF 128
#define BF 16
#define NH 4
#define HC 128
#define CC 32
#define DEPTH 5
#define NEG 0.2f
#define NPART 256
#define PTILE 4096
#define CTILE 1024

typedef __attribute__((ext_vector_type(8))) short bf16x8;
typedef __attribute__((ext_vector_type(4))) float f32x4;

__device__ inline unsigned short f2bf(float f) {
  union { float f; unsigned u; } v; v.f = f;
  unsigned r = v.u + 0x7fff + ((v.u >> 16) & 1);
  return (unsigned short)(r >> 16);
}
__device__ inline float bf2f(unsigned short u) {
  union { unsigned u; float f; } v; v.u = (unsigned)u << 16; return v.f;
}

// ---------------- CSR build (fully partition-local; no global deg atomics) ----
// partition histogram only, high-occupancy tiles
__global__ __launch_bounds__(256) void k_hist(const int* __restrict__ edst,
                                              int* __restrict__ pcnt) {
  __shared__ int lc[NPART];
  int t = threadIdx.x;
  lc[t] = 0;
  __syncthreads();
  int base = blockIdx.x * CTILE;
#pragma unroll
  for (int j = 0; j < CTILE / 256; ++j) {
    int e = base + t + j * 256;
    if (e < NE) atomicAdd(&lc[edst[e] >> 8], 1);
  }
  __syncthreads();
  if (lc[t]) atomicAdd(&pcnt[t], lc[t]);
}

__global__ void k_pscan(const int* __restrict__ pcnt, int* __restrict__ pbase,
                        int* __restrict__ pcur, int* __restrict__ offs) {
  __shared__ int s[NPART];
  int t = threadIdx.x;
  int v = pcnt[t];
  s[t] = v;
  __syncthreads();
  for (int d = 1; d < NPART; d <<= 1) {
    int x = (t >= d) ? s[t - d] : 0;
    __syncthreads();
    s[t] += x;
    __syncthreads();
  }
  int ex = s[t] - v;
  pbase[t] = ex;
  pcur[t] = ex;
  if (t == NPART - 1) {
    pbase[NPART] = s[NPART - 1];
    offs[NN] = NE;
  }
}

__global__ __launch_bounds__(256) void k_p1(const int* __restrict__ edst,
                                            int* __restrict__ pcur,
                                            int2* __restrict__ staging) {
  __shared__ int lc[NPART];
  __shared__ int lbase[NPART];
  __shared__ int lrank[NPART];
  int t = threadIdx.x;
  lc[t] = 0;
  __syncthreads();
  int base = blockIdx.x * PTILE;
  int myd[PTILE / 256];
#pragma unroll
  for (int j = 0; j < PTILE / 256; ++j) {
    int e = base + t + j * 256;
    int d = (e < NE) ? edst[e] : -1;
    myd[j] = d;
    if (d >= 0) atomicAdd(&lc[d >> 8], 1);
  }
  __syncthreads();
  if (lc[t]) lbase[t] = atomicAdd(&pcur[t], lc[t]);
  lrank[t] = 0;
  __syncthreads();
#pragma unroll
  for (int j = 0; j < PTILE / 256; ++j) {
    int d = myd[j];
    if (d >= 0) {
      int p = d >> 8;
      int r = atomicAdd(&lrank[p], 1);
      staging[lbase[p] + r] = make_int2(base + t + j * 256, d);
    }
  }
}

// per partition: LDS deg histogram -> local scan -> offs + csr_eid (all LDS atomics)
__global__ __launch_bounds__(256) void k_p2(const int2* __restrict__ staging,
                                            const int* __restrict__ pbase,
                                            int* __restrict__ offs,
                                            int* __restrict__ csr_eid) {
  __shared__ int ldeg[256];
  __shared__ int lofs[256];
  __shared__ int lcur[256];
  int p = blockIdx.x, t = threadIdx.x;
  int s = pbase[p], e = pbase[p + 1];
  ldeg[t] = 0;
  __syncthreads();
  for (int i = s + t; i < e; i += 256) atomicAdd(&ldeg[staging[i].y & 255], 1);
  __syncthreads();
  int v = ldeg[t];
  lofs[t] = v;
  __syncthreads();
  for (int d = 1; d < 256; d <<= 1) {
    int x = (t >= d) ? lofs[t - d] : 0;
    __syncthreads();
    lofs[t] += x;
    __syncthreads();
  }
  int myofs = s + lofs[t] - v;  // absolute exclusive offset
  int node = p * 256 + t;
  if (node < NN) offs[node] = myofs;
  lcur[t] = myofs;
  __syncthreads();
  for (int i = s + t; i < e; i += 256) {
    int2 st = staging[i];
    int slot = atomicAdd(&lcur[st.y & 255], 1);
    csr_eid[slot] = st.x;
  }
}

// ---------------- prep kernels (once) ----------------
__global__ void k_weff(const float* __restrict__ We, const float* __restrict__ ae,
                       float* __restrict__ weff) {
  int idx = threadIdx.x;
  if (idx >= DEPTH * BF * NH) return;
  int l = idx / (BF * NH);
  int r = idx - l * (BF * NH);
  int f = r >> 2, h = r & 3;
  const float* We_l = We + (size_t)l * BF * HC;
  const float* ae_l = ae + (size_t)l * NH * CC;
  float acc = 0.f;
  for (int c = 0; c < CC; ++c) acc += We_l[f * HC + h * CC + c] * ae_l[h * CC + c];
  weff[idx] = acc;
}

__global__ __launch_bounds__(256) void k_aeprep(const int* __restrict__ csr_eid,
                                                const int* __restrict__ esrc,
                                                const float* __restrict__ eattr,
                                                const float* __restrict__ weff,
                                                unsigned short* __restrict__ ae_csr,
                                                int* __restrict__ csr_src) {
  __shared__ float sw[DEPTH * BF * NH];
  int t = threadIdx.x;
  if (t < DEPTH * BF * NH) sw[t] = weff[t];
  __syncthreads();
  int i = blockIdx.x * 256 + t;
  if (i >= NE) return;
  int eid = csr_eid[i];
  csr_src[i] = esrc[eid];
  float at[16];
  const float4* ar = (const float4*)(eattr + (size_t)eid * BF);
#pragma unroll
  for (int q = 0; q < 4; ++q) {
    float4 v = ar[q];
    at[q * 4] = v.x; at[q * 4 + 1] = v.y; at[q * 4 + 2] = v.z; at[q * 4 + 3] = v.w;
  }
#pragma unroll
  for (int l = 0; l < DEPTH; ++l) {
    float a0 = 0.f, a1 = 0.f, a2 = 0.f, a3 = 0.f;
#pragma unroll
    for (int f = 0; f < BF; ++f) {
      float av = at[f];
      const float* wf = &sw[(l * BF + f) * NH];
      a0 += av * wf[0]; a1 += av * wf[1]; a2 += av * wf[2]; a3 += av * wf[3];
    }
    ushort4 u;
    u.x = f2bf(a0); u.y = f2bf(a1); u.z = f2bf(a2); u.w = f2bf(a3);
    ((ushort4*)ae_csr)[(size_t)l * NE + i] = u;
  }
}

__global__ void k_aeself(const unsigned short* __restrict__ ae_csr,
                         const int* __restrict__ offs,
                         unsigned short* __restrict__ ae_self) {
  int idx = blockIdx.x * 256 + threadIdx.x;
  if (idx >= NN * DEPTH) return;
  int l = idx / NN, n = idx - l * NN;
  int s = offs[n], e = offs[n + 1];
  const ushort4* base = (const ushort4*)ae_csr + (size_t)l * NE;
  float a0 = 0.f, a1 = 0.f, a2 = 0.f, a3 = 0.f;
  for (int i = s; i < e; ++i) {
    ushort4 u = base[i];
    a0 += bf2f(u.x); a1 += bf2f(u.y); a2 += bf2f(u.z); a3 += bf2f(u.w);
  }
  float inv = 1.0f / fmaxf((float)(e - s), 1.0f);
  ushort4 o;
  o.x = f2bf(a0 * inv); o.y = f2bf(a1 * inv); o.z = f2bf(a2 * inv); o.w = f2bf(a3 * inv);
  ((ushort4*)ae_self)[(size_t)l * NN + n] = o;
}

__global__ void k_x2bf(const float* __restrict__ x, unsigned short* __restrict__ xb) {
  int i = blockIdx.x * 256 + threadIdx.x;
  if (i >= NN * 32) return;
  float4 v = ((const float4*)x)[i];
  ushort4 u;
  u.x = f2bf(v.x); u.y = f2bf(v.y); u.z = f2bf(v.z); u.w = f2bf(v.w);
  ((ushort4*)xb)[i] = u;
}

__global__ void k_wprep(const float* __restrict__ W, unsigned short* __restrict__ Wt) {
  int idx = blockIdx.x * 256 + threadIdx.x;
  if (idx >= DEPTH * NF * HC) return;
  int l = idx >> 14;
  int rem = idx & 16383;
  int n = rem >> 7, k = rem & 127;
  Wt[(size_t)l * 16384 + (size_t)n * 128 + k] = f2bf(W[(size_t)l * 16384 + (size_t)k * 128 + n]);
}

// ---------------- per-layer kernels ----------------
// xp = A @ W via bf16 MFMA; 128-row x 128-col block, 4 waves (wave = 32-col strip).
// LDS C-tile epilogue: coalesced uint4 stores + a_s/a_d dots.
__global__ __launch_bounds__(256) void k_gemm_mfma(const unsigned short* __restrict__ Ab,
                                                   const unsigned short* __restrict__ Wt,
                                                   const float* __restrict__ as_w,
                                                   const float* __restrict__ ad_w,
                                                   unsigned short* __restrict__ xpb,
                                                   float* __restrict__ a_s,
                                                   float* __restrict__ a_d) {
  __shared__ unsigned short cl[128][144];
  __shared__ float swS[128], dwS[128];
  int t = threadIdx.x;
  if (t < 128) { swS[t] = as_w[t]; dwS[t] = ad_w[t]; }
  int wv = t >> 6;
  int l = t & 63;
  int r0 = blockIdx.x * 128;
  int lk = (l >> 4) * 8;
  int c0 = wv * 32;
  f32x4 acc[8][2] = {};
#pragma unroll
  for (int ks = 0; ks < 4; ++ks) {
    int kb = ks * 32 + lk;
    bf16x8 bfr0 = *(const bf16x8*)&Wt[(size_t)(c0 + (l & 15)) * 128 + kb];
    bf16x8 bfr1 = *(const bf16x8*)&Wt[(size_t)(c0 + 16 + (l & 15)) * 128 + kb];
#pragma unroll
    for (int rt = 0; rt < 8; ++rt) {
      int row = r0 + rt * 16 + (l & 15);
      row = row < NN ? row : NN - 1;
      bf16x8 afr = *(const bf16x8*)&Ab[(size_t)row * 128 + kb];
      acc[rt][0] = __builtin_amdgcn_mfma_f32_16x16x32_bf16(afr, bfr0, acc[rt][0], 0, 0, 0);
      acc[rt][1] = __builtin_amdgcn_mfma_f32_16x16x32_bf16(afr, bfr1, acc[rt][1], 0, 0, 0);
    }
  }
#pragma unroll
  for (int rt = 0; rt < 8; ++rt) {
#pragma unroll
    for (int j = 0; j < 4; ++j) {
      int lr = rt * 16 + (l >> 4) * 4 + j;
      cl[lr][c0 + (l & 15)] = f2bf(acc[rt][0][j]);
      cl[lr][c0 + 16 + (l & 15)] = f2bf(acc[rt][1][j]);
    }
  }
  __syncthreads();
  int row = t >> 1;
  int grow = r0 + row;
  int p = t & 1;
  if (grow < NN) {
    uint4* dst = (uint4*)&xpb[(size_t)grow * 128];
#pragma unroll
    for (int q = 0; q < 8; ++q)
      dst[q * 2 + p] = *(uint4*)&cl[row][(q * 2 + p) * 8];
  }
  int row2 = t >> 2;
  int hh = t & 3;
  int hc = hh * 32;
#pragma unroll
  for (int half = 0; half < 2; ++half) {
    int rr = row2 + half * 64;
    int gr = r0 + rr;
    float ps = 0.f, pd = 0.f;
#pragma unroll
    for (int q = 0; q < 4; ++q) {
      uint4 u = *(uint4*)&cl[rr][hc + q * 8];
      const unsigned short* us = (const unsigned short*)&u;
#pragma unroll
      for (int k = 0; k < 8; ++k) {
        float xv = bf2f(us[k]);
        ps += xv * swS[hc + q * 8 + k];
        pd += xv * dwS[hc + q * 8 + k];
      }
    }
    if (gr < NN) {
      a_s[(size_t)gr * 4 + hh] = ps;
      a_d[(size_t)gr * 4 + hh] = pd;
    }
  }
}

// 1 wave/node. 16-edge batches: lane (q=lane&15, h=lane>>4) computes ONE
// (edge,head) weight; weights+srcs distributed via __shfl. No-max exp (clamped).
__global__ __launch_bounds__(256) void k_aggr(const unsigned short* __restrict__ xpb,
                                              const unsigned short* __restrict__ ae_l,
                                              const unsigned short* __restrict__ aeself_l,
                                              const float* __restrict__ a_s,
                                              const float* __restrict__ a_d,
                                              const int* __restrict__ csr_src,
                                              const int* __restrict__ offs,
                                              const float* __restrict__ b_l,
                                              unsigned short* __restrict__ hout) {
  int node = blockIdx.x * 4 + (threadIdx.x >> 6);
  if (node >= NN) return;
  int lane = threadIdx.x & 63;
  int q = lane & 15;
  int h = lane >> 4;
  int base = lane & 48;  // 16*h
  const ushort2* xp2 = (const ushort2*)xpb;
  int s = offs[node], e = offs[node + 1];
  float ad = a_d[(size_t)node * 4 + h];
  float vs = a_s[(size_t)node * 4 + h] + ad + bf2f(aeself_l[(size_t)node * 4 + h]);
  vs = vs > 0.f ? vs : NEG * vs;
  float es = __expf(fminf(vs, 60.f));
  ushort2 xs = xp2[(size_t)node * 64 + lane];
  float acc0 = es * bf2f(xs.x), acc1 = es * bf2f(xs.y);
  float den = es;
  for (int i = s; i < e; i += 16) {
    int cnt = e - i;
    int srcv = 0;
    float w = 0.f;
    if (q < cnt) {
      srcv = csr_src[i + q];
      float a = a_s[(size_t)srcv * 4 + h] + ad + bf2f(ae_l[(size_t)(i + q) * 4 + h]);
      a = a > 0.f ? a : NEG * a;
      w = __expf(fminf(a, 60.f));
    }
#pragma unroll 8
    for (int qq = 0; qq < 16; ++qq) {
      int sq = __shfl(srcv, base | qq);
      float wq = __shfl(w, base | qq);
      ushort2 xq = xp2[(size_t)sq * 64 + lane];
      den += wq;
      acc0 += wq * bf2f(xq.x);
      acc1 += wq * bf2f(xq.y);
    }
  }
  float2 b2 = ((const float2*)b_l)[lane];
  float inv = 1.0f / (den + 1e-16f);
  float o0 = fmaxf(acc0 * inv + b2.x, 0.f);
  float o1 = fmaxf(acc1 * inv + b2.y, 0.f);
  ushort2 ho;
  ho.x = f2bf(o0); ho.y = f2bf(o1);
  ((ushort2*)hout)[(size_t)node * 64 + lane] = ho;
}

// out = relu([x, h] @ Wout + bout) — LDS-staged Wout; h is bf16.
__global__ __launch_bounds__(256) void k_final(const float* __restrict__ x,
                                               const unsigned short* __restrict__ h,
                                               const float* __restrict__ Wout, const float* __restrict__ bout,
                                               float* __restrict__ out) {
  __shared__ float4 wlds[2048];
  int t = threadIdx.x;
#pragma unroll
  for (int i = 0; i < 8; ++i) wlds[t + i * 256] = ((const float4*)Wout)[t + i * 256];
  __syncthreads();
  int tx = t & 7;
  int ty = t >> 3;
  int row0 = blockIdx.x * 64 + ty;
  int row1 = row0 + 32;
  bool v0 = row0 < NN, v1 = row1 < NN;
  const float4* x4 = (const float4*)x;
  const ushort4* h4 = (const ushort4*)h;
  float acc[2][4] = {};
  const float4 z = make_float4(0.f, 0.f, 0.f, 0.f);
#pragma unroll 4
  for (int k4 = 0; k4 < 32; ++k4) {
    float4 a0 = v0 ? x4[(size_t)row0 * 32 + k4] : z;
    float4 a1 = v1 ? x4[(size_t)row1 * 32 + k4] : z;
    float av0[4] = {a0.x, a0.y, a0.z, a0.w};
    float av1[4] = {a1.x, a1.y, a1.z, a1.w};
#pragma unroll
    for (int kk = 0; kk < 4; ++kk) {
      float4 w = wlds[(k4 * 4 + kk) * 8 + tx];
      acc[0][0] += av0[kk] * w.x; acc[0][1] += av0[kk] * w.y;
      acc[0][2] += av0[kk] * w.z; acc[0][3] += av0[kk] * w.w;
      acc[1][0] += av1[kk] * w.x; acc[1][1] += av1[kk] * w.y;
      acc[1][2] += av1[kk] * w.z; acc[1][3] += av1[kk] * w.w;
    }
  }
#pragma unroll 4
  for (int k4 = 0; k4 < 32; ++k4) {
    ushort4 u0 = v0 ? h4[(size_t)row0 * 32 + k4] : make_ushort4(0, 0, 0, 0);
    ushort4 u1 = v1 ? h4[(size_t)row1 * 32 + k4] : make_ushort4(0, 0, 0, 0);
    float av0[4] = {bf2f(u0.x), bf2f(u0.y), bf2f(u0.z), bf2f(u0.w)};
    float av1[4] = {bf2f(u1.x), bf2f(u1.y), bf2f(u1.z), bf2f(u1.w)};
#pragma unroll
    for (int kk = 0; kk < 4; ++kk) {
      float4 w = wlds[(128 + k4 * 4 + kk) * 8 + tx];
      acc[0][0] += av0[kk] * w.x; acc[0][1] += av0[kk] * w.y;
      acc[0][2] += av0[kk] * w.z; acc[0][3] += av0[kk] * w.w;
      acc[1][0] += av1[kk] * w.x; acc[1][1] += av1[kk] * w.y;
      acc[1][2] += av1[kk] * w.z; acc[1][3] += av1[kk] * w.w;
    }
  }
  float4 b4 = ((const float4*)bout)[tx];
  if (v0) {
    float4 o = make_float4(fmaxf(acc[0][0] + b4.x, 0.f), fmaxf(acc[0][1] + b4.y, 0.f),
                           fmaxf(acc[0][2] + b4.z, 0.f), fmaxf(acc[0][3] + b4.w, 0.f));
    ((float4*)out)[(size_t)row0 * 8 + tx] = o;
  }
  if (v1) {
    float4 o = make_float4(fmaxf(acc[1][0] + b4.x, 0.f), fmaxf(acc[1][1] + b4.y, 0.f),
                           fmaxf(acc[1][2] + b4.z, 0.f), fmaxf(acc[1][3] + b4.w, 0.f));
    ((float4*)out)[(size_t)row1 * 8 + tx] = o;
  }
}

extern "C" void kernel_launch(void* const* d_in, const int* in_sizes, int n_in,
                              void* d_out, int out_size, void* d_ws, size_t ws_size,
                              hipStream_t stream) {
  const float* x        = (const float*)d_in[0];
  const int*   eidx     = (const int*)d_in[1];
  const float* eattr    = (const float*)d_in[2];
  const float* W        = (const float*)d_in[3];
  const float* att_src  = (const float*)d_in[4];
  const float* att_dst  = (const float*)d_in[5];
  const float* We       = (const float*)d_in[6];
  const float* att_edge = (const float*)d_in[7];
  const float* b        = (const float*)d_in[8];
  const float* Wout     = (const float*)d_in[9];
  const float* bout     = (const float*)d_in[10];
  float* out = (float*)d_out;

  const int* esrc = eidx;
  const int* edst = eidx + NE;

  size_t off = 0;
  auto carve = [&](size_t bytes) {
    void* p = (char*)d_ws + off;
    off += (bytes + 255) & ~(size_t)255;
    return p;
  };
  unsigned short* h_buf   = (unsigned short*)carve((size_t)NN * HC * 2);  // bf16(x) for layer 0
  unsigned short* xpb     = (unsigned short*)carve((size_t)NN * HC * 2);
  unsigned short* Wt      = (unsigned short*)carve((size_t)DEPTH * NF * HC * 2);
  unsigned short* ae_csr  = (unsigned short*)carve((size_t)DEPTH * NE * NH * 2);
  unsigned short* ae_self = (unsigned short*)carve((size_t)DEPTH * NN * NH * 2);
  float* a_s   = (float*)carve((size_t)NN * NH * 4);
  float* a_d   = (float*)carve((size_t)NN * NH * 4);
  float* weff  = (float*)carve((size_t)DEPTH * BF * NH * 4);
  int* offs = (int*)carve((size_t)(NN + 1) * 4);
  int2* staging = (int2*)carve((size_t)NE * 8);
  int* csr_eid = (int*)carve((size_t)NE * 4);
  int* csr_src = (int*)carve((size_t)NE * 4);
  int* pcnt  = (int*)carve((size_t)NPART * 4);
  int* pbase = (int*)carve((size_t)(NPART + 1) * 4);
  int* pcur  = (int*)carve((size_t)NPART * 4);

  const int nbE = (NE + 255) / 256;
  const int nbP = (NE + PTILE - 1) / PTILE;
  const int nbC = (NE + CTILE - 1) / CTILE;

  hipMemsetAsync(pcnt, 0, (size_t)NPART * 4, stream);
  k_hist<<<nbC, 256, 0, stream>>>(edst, pcnt);
  k_pscan<<<1, NPART, 0, stream>>>(pcnt, pbase, pcur, offs);
  k_p1<<<nbP, 256, 0, stream>>>(edst, pcur, staging);
  k_p2<<<NPART, 256, 0, stream>>>(staging, pbase, offs, csr_eid);
  k_weff<<<1, 320, 0, stream>>>(We, att_edge, weff);
  k_aeprep<<<nbE, 256, 0, stream>>>(csr_eid, esrc, eattr, weff, ae_csr, csr_src);
  k_aeself<<<(NN * DEPTH + 255) / 256, 256, 0, stream>>>(ae_csr, offs, ae_self);
  k_x2bf<<<(NN * 32 + 255) / 256, 256, 0, stream>>>(x, h_buf);
  k_wprep<<<(DEPTH * NF * HC + 255) / 256, 256, 0, stream>>>(W, Wt);

  for (int l = 0; l < DEPTH; ++l) {
    k_gemm_mfma<<<(NN + 127) / 128, 256, 0, stream>>>(h_buf, Wt + (size_t)l * NF * HC,
                                                      att_src + (size_t)l * NH * CC,
                                                      att_dst + (size_t)l * NH * CC,
                                                      xpb, a_s, a_d);
    k_aggr<<<(NN + 3) / 4, 256, 0, stream>>>(xpb,
                                             ae_csr + (size_t)l * NE * NH,
                                             ae_self + (size_t)l * NN * NH,
                                             a_s, a_d, csr_src, offs,
                                             b + (size_t)l * HC, h_buf);
  }
  k_final<<<(NN + 63) / 64, 256, 0, stream>>>(x, h_buf, Wout, bout, out);
}